// Round 4
// baseline (366.180 us; speedup 1.0000x reference)
//
#include <hip/hip_runtime.h>

#define E_TOTAL   500000
#define NN        50000
#define ND        128
#define ED        128
#define HID       256
#define IND       384   /* 2*ND + ED */
#define EB        64
#define NBLOCKS   ((E_TOTAL + EB - 1) / EB)

typedef float  f32x4  __attribute__((ext_vector_type(4)));
typedef short  bf16x8 __attribute__((ext_vector_type(8)));

__device__ __forceinline__ unsigned short f2bf(float f) {
    unsigned int u = __float_as_uint(f);
    u += 0x7FFFu + ((u >> 16) & 1u);   // RNE
    return (unsigned short)(u >> 16);
}
__device__ __forceinline__ float bf2f(unsigned short h) {
    return __uint_as_float(((unsigned int)h) << 16);
}

// ---------------- prep: weights fp32 -> bf16 transposed ----------------
__global__ void prep_w1(const float* __restrict__ w1, unsigned short* __restrict__ w1t) {
    int i = blockIdx.x * blockDim.x + threadIdx.x;
    if (i >= IND * HID) return;
    int k = i / HID, n = i % HID;
    w1t[n * IND + k] = f2bf(w1[i]);       // W1T[n][k] = W1[k][n]
}

__global__ void prep_w2(const float* __restrict__ w2, unsigned short* __restrict__ w2t) {
    int i = blockIdx.x * blockDim.x + threadIdx.x;
    if (i >= HID * ED) return;
    int k = i / ED, n = i % ED;
    w2t[n * HID + k] = f2bf(w2[i]);       // W2T[n][k] = W2[k][n]
}

// ---------------- prep: per-node partial products ----------------
// Psrc[n][:] = nodes[n] @ W1[0:128, :] + b1   (bf16, 50000x256)
// Pdst[n][:] = nodes[n] @ W1[128:256, :]      (bf16, 50000x256)
__global__ __launch_bounds__(256, 2)
void prep_ptab(const float* __restrict__ nf,
               const unsigned short* __restrict__ w1t,
               const float* __restrict__ b1,
               unsigned short* __restrict__ Psrc,
               unsigned short* __restrict__ Pdst) {
    __shared__ unsigned short An[EB * ND];   // 16 KB swizzled
    const int tid  = threadIdx.x;
    const int base = blockIdx.x * EB;
    const int lane = tid & 63;
    const int w    = tid >> 6;
    const int l15  = lane & 15;
    const int lhi  = lane >> 4;

    #pragma unroll
    for (int it = 0; it < 4; ++it) {
        int item = tid + it * 256;          // 0..1023
        int row = item >> 4, cc = item & 15;
        int nidx = base + row;
        if (nidx >= NN) nidx = NN - 1;
        const float* p = nf + (size_t)nidx * ND + cc * 8;
        float4 f0 = *(const float4*)p;
        float4 f1 = *(const float4*)(p + 4);
        bf16x8 val;
        val[0] = (short)f2bf(f0.x); val[1] = (short)f2bf(f0.y);
        val[2] = (short)f2bf(f0.z); val[3] = (short)f2bf(f0.w);
        val[4] = (short)f2bf(f1.x); val[5] = (short)f2bf(f1.y);
        val[6] = (short)f2bf(f1.z); val[7] = (short)f2bf(f1.w);
        *(bf16x8*)(An + row * ND + ((cc * 8) ^ ((row & 7) * 8))) = val;
    }
    __syncthreads();

    f32x4 accs[4][4], accd[4][4];
    #pragma unroll
    for (int mt = 0; mt < 4; ++mt)
        #pragma unroll
        for (int nt = 0; nt < 4; ++nt) { accs[mt][nt] = (f32x4)0.0f; accd[mt][nt] = (f32x4)0.0f; }

    #pragma unroll
    for (int ks = 0; ks < 4; ++ks) {
        int c0 = ks * 32 + lhi * 8;
        bf16x8 a[4];
        #pragma unroll
        for (int mt = 0; mt < 4; ++mt) {
            int row = mt * 16 + l15;
            a[mt] = *(const bf16x8*)(An + row * ND + (c0 ^ ((row & 7) * 8)));
        }
        #pragma unroll
        for (int nt = 0; nt < 4; ++nt) {
            int n = w * 64 + nt * 16 + l15;
            bf16x8 bs = *(const bf16x8*)(w1t + (size_t)n * IND + c0);         // W1 rows 0:128
            bf16x8 bd = *(const bf16x8*)(w1t + (size_t)n * IND + 128 + c0);   // W1 rows 128:256
            #pragma unroll
            for (int mt = 0; mt < 4; ++mt) {
                accs[mt][nt] = __builtin_amdgcn_mfma_f32_16x16x32_bf16(a[mt], bs, accs[mt][nt], 0, 0, 0);
                accd[mt][nt] = __builtin_amdgcn_mfma_f32_16x16x32_bf16(a[mt], bd, accd[mt][nt], 0, 0, 0);
            }
        }
    }

    #pragma unroll
    for (int nt = 0; nt < 4; ++nt) {
        int col = w * 64 + nt * 16 + l15;
        float bias = b1[col];
        #pragma unroll
        for (int mt = 0; mt < 4; ++mt) {
            #pragma unroll
            for (int r = 0; r < 4; ++r) {
                int row = mt * 16 + lhi * 4 + r;
                int nidx = base + row;
                if (nidx < NN) {
                    size_t off = (size_t)nidx * HID + col;
                    Psrc[off] = f2bf(accs[mt][nt][r] + bias);
                    Pdst[off] = f2bf(accd[mt][nt][r]);
                }
            }
        }
    }
}

// ---------------- main fused kernel ----------------
// LDS: Ae [64][128] bf16 swizzled (edge features, residual source),
//      Ps/Pd [64][256] bf16 each, DMA-filled by global_load_lds with the
//      XOR swizzle applied to the per-lane GLOBAL address (LDS dest linear).
// Schedule: idx loads -> W1 B-frag loads -> edgef loads -> [sched fence] ->
// 16 P-gather DMAs -> [fence] -> Ae convert+write -> lgkm barrier ->
// GEMM1 (under DMA flight) -> vmcnt(0) barrier -> relu-merge -> barrier ->
// GEMM2 -> epilogue. No __syncthreads(): raw barriers keep DMAs in flight.
__global__ __launch_bounds__(256, 2)
void edge_mlp(const float* __restrict__ edgef,
              const int* __restrict__ eidx,
              const unsigned short* __restrict__ Psrc,
              const unsigned short* __restrict__ Pdst,
              const unsigned short* __restrict__ w1t,
              const unsigned short* __restrict__ w2t,
              const float* __restrict__ b2,
              float* __restrict__ out) {
    __shared__ unsigned short Ae[EB * ND];    // 16 KB
    __shared__ unsigned short Ps[EB * HID];   // 32 KB
    __shared__ unsigned short Pd[EB * HID];   // 32 KB

    const int tid  = threadIdx.x;
    const int base = blockIdx.x * EB;
    const int lane = tid & 63;
    const int w    = tid >> 6;
    const int l15  = lane & 15;
    const int lhi  = lane >> 4;
    const int rsub = lane >> 5;              // 0/1: which row of the DMA pair
    const int cc32 = lane & 31;              // 16B chunk within a 512B row
    const int* srcI = eidx;
    const int* dstI = eidx + E_TOTAL;

    // ---- 1. per-lane indices for this wave's 16 gather rows ----
    int sI[8], dI[8];
    #pragma unroll
    for (int i = 0; i < 8; ++i) {
        int row = w * 16 + 2 * i + rsub;
        int e = base + row;
        int el = e < E_TOTAL ? e : E_TOTAL - 1;
        sI[i] = srcI[el];
        dI[i] = dstI[el];
    }

    // ---- 2. preload GEMM1 B-fragments (W1 edge slice, L2-hot) ----
    bf16x8 bfr[4][4];                        // [nt][ks], 64 VGPR
    #pragma unroll
    for (int nt = 0; nt < 4; ++nt) {
        int n = w * 64 + nt * 16 + l15;
        #pragma unroll
        for (int ks = 0; ks < 4; ++ks)
            bfr[nt][ks] = *(const bf16x8*)(w1t + (size_t)n * IND + 256 + ks * 32 + lhi * 8);
    }

    // ---- 3. issue edge-feature loads (consumed in step 5) ----
    float4 ae0[4], ae1[4];
    #pragma unroll
    for (int it = 0; it < 4; ++it) {
        int item = tid + it * 256;           // 0..1023
        int row = item >> 4, cc = item & 15;
        int e = base + row;
        int el = e < E_TOTAL ? e : E_TOTAL - 1;
        const float* p = edgef + (size_t)el * ED + cc * 8;
        ae0[it] = *(const float4*)p;
        ae1[it] = *(const float4*)(p + 4);
    }

    // keep all pure loads issued BEFORE the DMAs (vmcnt is a FIFO: a load
    // issued after the DMAs would force vmcnt(0) = full DMA drain to use it)
    __builtin_amdgcn_sched_barrier(0);

    // ---- 4. issue 16 P-gather DMAs (global -> LDS, 1KB each) ----
    // LDS dest linear: lane l writes bytes [l*16, l*16+16) of a 1KB span =
    // rows {2i, 2i+1} x 32 chunks. Swizzle is applied to the GLOBAL chunk:
    // LDS[row][cc] = P[idx[row]][cc ^ (row&7)]  (16B-chunk units)
    #pragma unroll
    for (int i = 0; i < 8; ++i) {
        int row = w * 16 + 2 * i + rsub;
        int ccs = cc32 ^ (row & 7);
        const unsigned short* gs = Psrc + (size_t)sI[i] * HID + ccs * 8;
        const unsigned short* gd = Pdst + (size_t)dI[i] * HID + ccs * 8;
        unsigned short* ls = Ps + (w * 16 + 2 * i) * HID;
        unsigned short* ld_ = Pd + (w * 16 + 2 * i) * HID;
        __builtin_amdgcn_global_load_lds(
            (const __attribute__((address_space(1))) unsigned int*)gs,
            (__attribute__((address_space(3))) unsigned int*)ls, 16, 0, 0);
        __builtin_amdgcn_global_load_lds(
            (const __attribute__((address_space(1))) unsigned int*)gd,
            (__attribute__((address_space(3))) unsigned int*)ld_, 16, 0, 0);
    }

    // DMAs must be issued before the convert phase waits on the edgef data
    __builtin_amdgcn_sched_barrier(0);

    // ---- 5. convert + write Ae (waits vmcnt(16): DMAs stay in flight) ----
    #pragma unroll
    for (int it = 0; it < 4; ++it) {
        int item = tid + it * 256;
        int row = item >> 4, cc = item & 15;
        bf16x8 val;
        val[0] = (short)f2bf(ae0[it].x); val[1] = (short)f2bf(ae0[it].y);
        val[2] = (short)f2bf(ae0[it].z); val[3] = (short)f2bf(ae0[it].w);
        val[4] = (short)f2bf(ae1[it].x); val[5] = (short)f2bf(ae1[it].y);
        val[6] = (short)f2bf(ae1[it].z); val[7] = (short)f2bf(ae1[it].w);
        *(bf16x8*)(Ae + row * ND + ((cc * 8) ^ ((row & 7) * 8))) = val;
    }
    asm volatile("s_waitcnt lgkmcnt(0)" ::: "memory");   // my Ae writes done
    __builtin_amdgcn_s_barrier();                        // Ae visible; DMAs flying

    // ---- 6. GEMM1: acc1(64x256) = Ae(64x128) @ W1[256:384,:] ----
    f32x4 acc1[4][4];
    #pragma unroll
    for (int mt = 0; mt < 4; ++mt)
        #pragma unroll
        for (int nt = 0; nt < 4; ++nt)
            acc1[mt][nt] = (f32x4)0.0f;

    #pragma unroll
    for (int ks = 0; ks < 4; ++ks) {
        int c0 = ks * 32 + lhi * 8;
        bf16x8 a[4];
        #pragma unroll
        for (int mt = 0; mt < 4; ++mt) {
            int row = mt * 16 + l15;
            a[mt] = *(const bf16x8*)(Ae + row * ND + (c0 ^ ((row & 7) * 8)));
        }
        #pragma unroll
        for (int nt = 0; nt < 4; ++nt)
            #pragma unroll
            for (int mt = 0; mt < 4; ++mt)
                acc1[mt][nt] = __builtin_amdgcn_mfma_f32_16x16x32_bf16(a[mt], bfr[nt][ks], acc1[mt][nt], 0, 0, 0);
    }

    // ---- 7. drain DMAs, make Ps/Pd visible ----
    __builtin_amdgcn_sched_barrier(0);       // keep GEMM1 above the drain
    asm volatile("s_waitcnt vmcnt(0) lgkmcnt(0)" ::: "memory");
    __builtin_amdgcn_s_barrier();

    // ---- 8. relu-merge: Ps = relu(acc1 + Ps + Pd)  (b1 folded in Psrc) ----
    #pragma unroll
    for (int nt = 0; nt < 4; ++nt) {
        int col = w * 64 + nt * 16 + l15;
        #pragma unroll
        for (int mt = 0; mt < 4; ++mt) {
            #pragma unroll
            for (int r = 0; r < 4; ++r) {
                int row = mt * 16 + lhi * 4 + r;
                int idx = row * HID + (col ^ ((row & 7) * 8));
                float v = acc1[mt][nt][r] + bf2f(Ps[idx]) + bf2f(Pd[idx]);
                v = v > 0.0f ? v : 0.0f;
                Ps[idx] = f2bf(v);
            }
        }
    }
    asm volatile("s_waitcnt lgkmcnt(0)" ::: "memory");
    __builtin_amdgcn_s_barrier();

    // ---- 9. GEMM2: U(64x128) = Ps(64x256) @ W2 ----
    f32x4 acc2[4][2];
    #pragma unroll
    for (int mt = 0; mt < 4; ++mt)
        #pragma unroll
        for (int nt = 0; nt < 2; ++nt)
            acc2[mt][nt] = (f32x4)0.0f;

    #pragma unroll
    for (int ks = 0; ks < 8; ++ks) {
        int c0 = ks * 32 + lhi * 8;
        bf16x8 a[4];
        #pragma unroll
        for (int mt = 0; mt < 4; ++mt) {
            int row = mt * 16 + l15;
            a[mt] = *(const bf16x8*)(Ps + row * HID + (c0 ^ ((row & 7) * 8)));
        }
        #pragma unroll
        for (int nt = 0; nt < 2; ++nt) {
            int n = w * 32 + nt * 16 + l15;
            bf16x8 b = *(const bf16x8*)(w2t + (size_t)n * HID + c0);
            #pragma unroll
            for (int mt = 0; mt < 4; ++mt)
                acc2[mt][nt] = __builtin_amdgcn_mfma_f32_16x16x32_bf16(a[mt], b, acc2[mt][nt], 0, 0, 0);
        }
    }

    // ---- 10. epilogue: out = Ae(bf16 edge) + update + b2 ----
    #pragma unroll
    for (int nt = 0; nt < 2; ++nt) {
        int col = w * 32 + nt * 16 + l15;
        float bias = b2[col];
        #pragma unroll
        for (int mt = 0; mt < 4; ++mt) {
            #pragma unroll
            for (int r = 0; r < 4; ++r) {
                int row = mt * 16 + lhi * 4 + r;
                int e = base + row;
                if (e < E_TOTAL) {
                    float ev = bf2f(Ae[row * ND + (col ^ ((row & 7) * 8))]);
                    out[(size_t)e * ED + col] = ev + acc2[mt][nt][r] + bias;
                }
            }
        }
    }
}

extern "C" void kernel_launch(void* const* d_in, const int* in_sizes, int n_in,
                              void* d_out, int out_size, void* d_ws, size_t ws_size,
                              hipStream_t stream) {
    const float* nf   = (const float*)d_in[0];
    const float* ef   = (const float*)d_in[1];
    const int*   eidx = (const int*)d_in[2];
    const float* W1   = (const float*)d_in[3];
    const float* b1   = (const float*)d_in[4];
    const float* W2   = (const float*)d_in[5];
    const float* b2   = (const float*)d_in[6];
    float* out = (float*)d_out;

    unsigned short* w1t  = (unsigned short*)d_ws;          // 192 KB
    unsigned short* w2t  = w1t + IND * HID;                // 64 KB
    unsigned short* Psrc = w2t + HID * ED;                 // 25.6 MB
    unsigned short* Pdst = Psrc + (size_t)NN * HID;        // 25.6 MB

    prep_w1<<<(IND * HID + 255) / 256, 256, 0, stream>>>(W1, w1t);
    prep_w2<<<(HID * ED + 255) / 256, 256, 0, stream>>>(W2, w2t);
    prep_ptab<<<(NN + EB - 1) / EB, 256, 0, stream>>>(nf, w1t, b1, Psrc, Pdst);
    edge_mlp<<<NBLOCKS, 256, 0, stream>>>(ef, eidx, Psrc, Pdst, w1t, w2t, b2, out);
}